// Round 1
// baseline (719.835 us; speedup 1.0000x reference)
//
#include <hip/hip_runtime.h>
#include <hip/hip_bf16.h>

// BitLinearSTE: out[m][o] = sum_k x[m][k] * sign(w[o][k])
// M=8192 (4*2048), N=4096, K=4096. fp32 in/out; bf16 MFMA internally.

#define M_DIM 8192
#define N_DIM 4096
#define K_DIM 4096
#define BM 128
#define BN 128
#define BK 32
#define TILES_N (N_DIM / BN)  // 32
#define TILES_M (M_DIM / BM)  // 64

typedef __bf16 bf16x8 __attribute__((ext_vector_type(8)));
typedef __bf16 bf16x4 __attribute__((ext_vector_type(4)));
typedef float f32x4 __attribute__((ext_vector_type(4)));

__device__ __forceinline__ void gload_lds16(const __bf16* g, __bf16* l) {
    // async global->LDS, 16B per lane; LDS dest must be wave-uniform base (HW adds lane*16)
    __builtin_amdgcn_global_load_lds(
        (const __attribute__((address_space(1))) void*)g,
        (__attribute__((address_space(3))) void*)l,
        16, 0, 0);
}

// x fp32 -> bf16 (RNE), vectorized 4/thread
__global__ __launch_bounds__(256) void quant_x_k(const float* __restrict__ x,
                                                 __bf16* __restrict__ xq, int n4) {
    int stride = gridDim.x * blockDim.x;
    for (int i = blockIdx.x * blockDim.x + threadIdx.x; i < n4; i += stride) {
        float4 v = reinterpret_cast<const float4*>(x)[i];
        bf16x4 o;
        o[0] = (__bf16)v.x; o[1] = (__bf16)v.y; o[2] = (__bf16)v.z; o[3] = (__bf16)v.w;
        *reinterpret_cast<bf16x4*>(xq + 4 * (size_t)i) = o;
    }
}

// w fp32 -> sign(w) in bf16 (+1/-1/0 all exact)
__global__ __launch_bounds__(256) void quant_w_k(const float* __restrict__ w,
                                                 __bf16* __restrict__ wq, int n4) {
    int stride = gridDim.x * blockDim.x;
    for (int i = blockIdx.x * blockDim.x + threadIdx.x; i < n4; i += stride) {
        float4 v = reinterpret_cast<const float4*>(w)[i];
        bf16x4 o;
        o[0] = (__bf16)((v.x > 0.f) ? 1.f : ((v.x < 0.f) ? -1.f : 0.f));
        o[1] = (__bf16)((v.y > 0.f) ? 1.f : ((v.y < 0.f) ? -1.f : 0.f));
        o[2] = (__bf16)((v.z > 0.f) ? 1.f : ((v.z < 0.f) ? -1.f : 0.f));
        o[3] = (__bf16)((v.w > 0.f) ? 1.f : ((v.w < 0.f) ? -1.f : 0.f));
        *reinterpret_cast<bf16x4*>(wq + 4 * (size_t)i) = o;
    }
}

// m97-structure GEMM: C[M][N] = A[M][K] * B[N][K]^T, bf16 in, fp32 out.
// 128x128 tile, BK=32, 4 waves (2x2), each wave 64x64 via 4x4 16x16x32 MFMA frags.
__global__ __launch_bounds__(256) void gemm_bt_k(const __bf16* __restrict__ A,
                                                 const __bf16* __restrict__ B,
                                                 float* __restrict__ C) {
    __shared__ __bf16 As[BM * BK];  // 8 KB, linear (global_load_lds needs linear dest)
    __shared__ __bf16 Bs[BN * BK];  // 8 KB

    // XCD-aware bijective swizzle (nwg = 2048, divisible by 8)
    int bid = blockIdx.x;
    int cpx = (TILES_M * TILES_N) >> 3;
    int swz = (bid & 7) * cpx + (bid >> 3);
    int bm = swz / TILES_N;
    int bn = swz % TILES_N;
    int brow = bm * BM;
    int bcol = bn * BN;

    int tid = threadIdx.x;
    int wave = tid >> 6;
    int lane = tid & 63;
    int lr = lane & 15;   // fragment row/col within 16
    int lq = lane >> 4;   // 0..3: k-group / acc row group

    int row0 = (wave >> 1) * 64;  // wave's output sub-tile origin in tile
    int col0 = (wave & 1) * 64;

    f32x4 acc[4][4];
#pragma unroll
    for (int m = 0; m < 4; m++)
#pragma unroll
        for (int n = 0; n < 4; n++) acc[m][n] = (f32x4)(0.f);

    // Staging: tile = 128 rows x 32 cols bf16 = 8192B = 8 chunks of 1024B (16 rows).
    // Wave w stages chunks 2w, 2w+1 of both A and B.
    // Within a chunk, lane covers bytes lane*16: row = c*16 + lane/4, col = (lane&3)*8.
    int c0 = wave * 2;
    int srow0 = c0 * 16 + (lane >> 2);
    int srow1 = srow0 + 16;
    int scol = (lane & 3) * 8;

    const __bf16* agp0 = A + (size_t)(brow + srow0) * K_DIM + scol;
    const __bf16* agp1 = A + (size_t)(brow + srow1) * K_DIM + scol;
    const __bf16* bgp0 = B + (size_t)(bcol + srow0) * K_DIM + scol;
    const __bf16* bgp1 = B + (size_t)(bcol + srow1) * K_DIM + scol;
    __bf16* alp0 = As + c0 * 512;        // wave-uniform LDS chunk bases
    __bf16* alp1 = As + (c0 + 1) * 512;
    __bf16* blp0 = Bs + c0 * 512;
    __bf16* blp1 = Bs + (c0 + 1) * 512;

    for (int k0 = 0; k0 < K_DIM; k0 += BK) {
        gload_lds16(agp0 + k0, alp0);
        gload_lds16(agp1 + k0, alp1);
        gload_lds16(bgp0 + k0, blp0);
        gload_lds16(bgp1 + k0, blp1);
        __syncthreads();  // drains vmcnt(0): staged data visible

        bf16x8 a[4], b[4];
#pragma unroll
        for (int m = 0; m < 4; m++)
            a[m] = *reinterpret_cast<const bf16x8*>(As + (row0 + m * 16 + lr) * BK + lq * 8);
#pragma unroll
        for (int n = 0; n < 4; n++)
            b[n] = *reinterpret_cast<const bf16x8*>(Bs + (col0 + n * 16 + lr) * BK + lq * 8);
#pragma unroll
        for (int m = 0; m < 4; m++)
#pragma unroll
            for (int n = 0; n < 4; n++)
                acc[m][n] = __builtin_amdgcn_mfma_f32_16x16x32_bf16(a[m], b[n], acc[m][n], 0, 0, 0);

        __syncthreads();  // all reads done before next-iter overwrite
    }

    // Epilogue: C/D layout (m89-verified): col = lane&15, row = (lane>>4)*4 + reg
#pragma unroll
    for (int m = 0; m < 4; m++)
#pragma unroll
        for (int n = 0; n < 4; n++) {
            size_t grow = (size_t)(brow + row0 + m * 16 + lq * 4);
            size_t gcol = (size_t)(bcol + col0 + n * 16 + lr);
            float* cp = C + grow * N_DIM + gcol;
#pragma unroll
            for (int j = 0; j < 4; j++) cp[(size_t)j * N_DIM] = acc[m][n][j];
        }
}

extern "C" void kernel_launch(void* const* d_in, const int* in_sizes, int n_in,
                              void* d_out, int out_size, void* d_ws, size_t ws_size,
                              hipStream_t stream) {
    const float* x = (const float*)d_in[0];   // [4,2048,4096] fp32
    const float* w = (const float*)d_in[1];   // [4096,4096] fp32
    float* out = (float*)d_out;               // [4,2048,4096] fp32

    __bf16* xq = (__bf16*)d_ws;                         // 8192*4096*2 = 64 MiB
    __bf16* wq = xq + (size_t)M_DIM * K_DIM;            // 4096*4096*2 = 32 MiB

    quant_x_k<<<2048, 256, 0, stream>>>(x, xq, (M_DIM * K_DIM) / 4);
    quant_w_k<<<2048, 256, 0, stream>>>(w, wq, (N_DIM * K_DIM) / 4);
    gemm_bt_k<<<TILES_M * TILES_N, 256, 0, stream>>>(xq, wq, out);
}

// Round 2
// 476.647 us; speedup vs baseline: 1.5102x; 1.5102x over previous
//
#include <hip/hip_runtime.h>
#include <hip/hip_bf16.h>

// BitLinearSTE: out[m][o] = sum_k x[m][k] * sign(w[o][k])
// M=8192, N=4096, K=4096. fp32 in/out; bf16 MFMA internally.
// GEMM: 256x256 tile, BK=64, 8 waves (2Mx4N), 4-phase-per-K-tile schedule
// with counted vmcnt (T3+T4), st-swizzled LDS (T2), setprio (T5), XCD swizzle (T1).

#define M_DIM 8192
#define N_DIM 4096
#define K_DIM 4096
#define BM 256
#define BN 256
#define BK 64
#define NT (K_DIM / BK)        // 64 K-tiles
#define TILES_M (M_DIM / BM)   // 32
#define TILES_N (N_DIM / BN)   // 16

typedef __bf16 bf16x8 __attribute__((ext_vector_type(8)));
typedef float f32x4 __attribute__((ext_vector_type(4)));

__device__ __forceinline__ void gload_lds16(const __bf16* g, __bf16* l) {
    // async global->LDS, 16B/lane; LDS dest wave-uniform base (HW adds lane*16)
    __builtin_amdgcn_global_load_lds(
        (const __attribute__((address_space(1))) void*)g,
        (__attribute__((address_space(3))) void*)l, 16, 0, 0);
}

// ---------------- quantize kernels (memory-bound) ----------------

__global__ __launch_bounds__(256) void quant_x_k(const float* __restrict__ x,
                                                 __bf16* __restrict__ xq, int n8) {
    int stride = gridDim.x * blockDim.x;
    for (int i = blockIdx.x * blockDim.x + threadIdx.x; i < n8; i += stride) {
        float4 v0 = reinterpret_cast<const float4*>(x)[2 * (size_t)i];
        float4 v1 = reinterpret_cast<const float4*>(x)[2 * (size_t)i + 1];
        bf16x8 o;
        o[0] = (__bf16)v0.x; o[1] = (__bf16)v0.y; o[2] = (__bf16)v0.z; o[3] = (__bf16)v0.w;
        o[4] = (__bf16)v1.x; o[5] = (__bf16)v1.y; o[6] = (__bf16)v1.z; o[7] = (__bf16)v1.w;
        *reinterpret_cast<bf16x8*>(xq + 8 * (size_t)i) = o;
    }
}

__global__ __launch_bounds__(256) void quant_w_k(const float* __restrict__ w,
                                                 __bf16* __restrict__ wq, int n8) {
    int stride = gridDim.x * blockDim.x;
    for (int i = blockIdx.x * blockDim.x + threadIdx.x; i < n8; i += stride) {
        float4 v0 = reinterpret_cast<const float4*>(w)[2 * (size_t)i];
        float4 v1 = reinterpret_cast<const float4*>(w)[2 * (size_t)i + 1];
        float f[8] = {v0.x, v0.y, v0.z, v0.w, v1.x, v1.y, v1.z, v1.w};
        bf16x8 o;
#pragma unroll
        for (int j = 0; j < 8; ++j)
            o[j] = (__bf16)((f[j] > 0.f) ? 1.f : ((f[j] < 0.f) ? -1.f : 0.f));
        *reinterpret_cast<bf16x8*>(wq + 8 * (size_t)i) = o;
    }
}

// ---------------- 256^2 8-phase GEMM ----------------
// C[M][N] = A[M][K] * B[N][K]^T, bf16 in, fp32 out.
// LDS: As[2 buf][2 half][128*64], Bs same = 128 KiB dynamic.
// Swizzle (T2): LDS (row, slot16B) holds global (row, slot ^ (row&7));
// staged via pre-swizzled per-lane GLOBAL address (linear gload_lds dest, rule 21),
// read back with the same XOR. row&7 == lr&7 for all fragments (16-row aligned).

__global__ __launch_bounds__(512, 2) void gemm256_k(const __bf16* __restrict__ A,
                                                    const __bf16* __restrict__ B,
                                                    float* __restrict__ C) {
    extern __shared__ __bf16 sm[];
    __bf16* As = sm;            // [buf][half][128*64] : (b*2+h)*8192
    __bf16* Bs = sm + 32768;

    // T1: bijective XCD swizzle (nwg = 512, divisible by 8)
    int bid = blockIdx.x;
    int cpx = (TILES_M * TILES_N) >> 3;      // 64
    int swz = (bid & 7) * cpx + (bid >> 3);
    int bm = swz / TILES_N, bn = swz % TILES_N;
    const __bf16* Ag = A + (size_t)bm * BM * K_DIM;
    const __bf16* Bg = B + (size_t)bn * BN * K_DIM;

    int tid = threadIdx.x;
    int wave = tid >> 6, lane = tid & 63;
    int wm = wave >> 2, wn = wave & 3;       // wave -> (M half, N quarter)
    int lr = lane & 15, lq = lane >> 4;
    int laneRow = lane >> 3;                              // 0..7 (staging row within chunk)
    int gslot8 = (((lane & 7) ^ laneRow) << 3);           // pre-swizzled global col (elems)
    int swc0 = ((0 * 4 + lq) ^ (lr & 7)) << 3;            // ks=0 swizzled read col (elems)
    int swc1 = ((1 * 4 + lq) ^ (lr & 7)) << 3;            // ks=1

    f32x4 acc[8][4];
#pragma unroll
    for (int m = 0; m < 8; ++m)
#pragma unroll
        for (int n = 0; n < 4; ++n) acc[m][n] = (f32x4)(0.f);

    // Stage one 128-row half-tile: 16 chunks of 8 rows (1024B); wave w does chunks w, w+8.
#define STAGE(gbase, ldsbase, kt_) do {                                               \
        const __bf16* g0_ = (gbase) + (size_t)(wave * 8 + laneRow) * K_DIM            \
                            + ((kt_) * BK + gslot8);                                  \
        gload_lds16(g0_, (ldsbase) + wave * 512);                                     \
        gload_lds16(g0_ + (size_t)64 * K_DIM, (ldsbase) + (wave + 8) * 512);          \
    } while (0)

    // Prologue: B(0)->buf0, A(0)->buf0, B(1)->buf1; wait all but B(1) (4 calls in flight).
    STAGE(Bg, Bs + 0 * 8192, 0);                       // B(0) half 0 -> buf0
    STAGE(Bg + (size_t)128 * K_DIM, Bs + 1 * 8192, 0); // B(0) half 1
    STAGE(Ag, As + 0 * 8192, 0);                       // A(0) half 0 -> buf0
    STAGE(Ag + (size_t)128 * K_DIM, As + 1 * 8192, 0); // A(0) half 1
    STAGE(Bg, Bs + 2 * 8192, 1);                       // B(1) half 0 -> buf1
    STAGE(Bg + (size_t)128 * K_DIM, Bs + 3 * 8192, 1); // B(1) half 1
    asm volatile("s_waitcnt vmcnt(4)" ::: "memory");
    __builtin_amdgcn_s_barrier();

    for (int kt = 0; kt < NT; ++kt) {
        int b = kt & 1;
        int ktn = (kt + 1) & (NT - 1);   // wrap: epilogue stages land in dead regions
        int ktnn = (kt + 2) & (NT - 1);
        const __bf16* ap = As + (b * 2 + wm) * 8192;
        const __bf16* bp = Bs + (b * 2 + (wn >> 1)) * 8192;
        int brow_ = (wn & 1) * 64;

        bf16x8 bfr[4][2];
#pragma unroll
        for (int q = 0; q < 4; ++q) {
            // --- ds reads for this phase ---
            bf16x8 afr[2][2];
#pragma unroll
            for (int m2 = 0; m2 < 2; ++m2) {
                const __bf16* r = ap + ((2 * q + m2) * 16 + lr) * 64;
                afr[m2][0] = *reinterpret_cast<const bf16x8*>(r + swc0);
                afr[m2][1] = *reinterpret_cast<const bf16x8*>(r + swc1);
            }
            if (q == 0) {
#pragma unroll
                for (int n = 0; n < 4; ++n) {
                    const __bf16* r = bp + (brow_ + n * 16 + lr) * 64;
                    bfr[n][0] = *reinterpret_cast<const bf16x8*>(r + swc0);
                    bfr[n][1] = *reinterpret_cast<const bf16x8*>(r + swc1);
                }
            }
            // --- stage one half-tile (region consumed >= 1 barrier ago) ---
            if (q == 0)      STAGE(Ag,                         As + ((b ^ 1) * 2 + 0) * 8192, ktn);
            else if (q == 1) STAGE(Ag + (size_t)128 * K_DIM,   As + ((b ^ 1) * 2 + 1) * 8192, ktn);
            else if (q == 2) STAGE(Bg,                         Bs + (b * 2 + 0) * 8192, ktnn);
            else             STAGE(Bg + (size_t)128 * K_DIM,   Bs + (b * 2 + 1) * 8192, ktnn);

            __builtin_amdgcn_s_barrier();
            asm volatile("s_waitcnt lgkmcnt(0)" ::: "memory");
            __builtin_amdgcn_s_setprio(1);
#pragma unroll
            for (int m2 = 0; m2 < 2; ++m2)
#pragma unroll
                for (int n = 0; n < 4; ++n)
#pragma unroll
                    for (int ks = 0; ks < 2; ++ks)
                        acc[2 * q + m2][n] = __builtin_amdgcn_mfma_f32_16x16x32_bf16(
                            afr[m2][ks], bfr[n][ks], acc[2 * q + m2][n], 0, 0, 0);
            __builtin_amdgcn_s_setprio(0);
            if (q == 3) asm volatile("s_waitcnt vmcnt(4)" ::: "memory"); // counted: B(kt+2) stays in flight
            __builtin_amdgcn_s_barrier();
        }
    }
#undef STAGE

    // Epilogue: C/D layout col=lane&15, row=(lane>>4)*4+j (m89-verified)
    size_t crow0 = (size_t)bm * BM + wm * 128 + lq * 4;
    size_t ccol0 = (size_t)bn * BN + wn * 64 + lr;
#pragma unroll
    for (int m = 0; m < 8; ++m)
#pragma unroll
        for (int n = 0; n < 4; ++n) {
            float* cp = C + (crow0 + m * 16) * N_DIM + (ccol0 + n * 16);
#pragma unroll
            for (int j = 0; j < 4; ++j) cp[(size_t)j * N_DIM] = acc[m][n][j];
        }
}

extern "C" void kernel_launch(void* const* d_in, const int* in_sizes, int n_in,
                              void* d_out, int out_size, void* d_ws, size_t ws_size,
                              hipStream_t stream) {
    const float* x = (const float*)d_in[0];   // [4,2048,4096] fp32
    const float* w = (const float*)d_in[1];   // [4096,4096] fp32
    float* out = (float*)d_out;               // [4,2048,4096] fp32

    __bf16* xq = (__bf16*)d_ws;                         // 64 MiB
    __bf16* wq = xq + (size_t)M_DIM * K_DIM;            // 32 MiB

    // 128 KiB dynamic LDS opt-in (host-side attribute; capture-safe, idempotent)
    hipFuncSetAttribute((const void*)gemm256_k,
                        hipFuncAttributeMaxDynamicSharedMemorySize, 131072);

    quant_x_k<<<2048, 256, 0, stream>>>(x, xq, (M_DIM * K_DIM) / 8);
    quant_w_k<<<1024, 256, 0, stream>>>(w, wq, (N_DIM * K_DIM) / 8);
    gemm256_k<<<TILES_M * TILES_N, 512, 131072, stream>>>(xq, wq, out);
}